// Round 5
// baseline (214.724 us; speedup 1.0000x reference)
//
#include <hip/hip_runtime.h>

#define CAP 64
#define BCAP 4096         // entries per bin region (mean ~3070, ~18 sigma headroom)
#define RADIX_UNITS 4096  // int2 units per radix block = 8192 edges = 16/thread

typedef short bf16x8 __attribute__((ext_vector_type(8)));
typedef float f32x4 __attribute__((ext_vector_type(4)));
typedef unsigned short u16;
typedef unsigned int u32;

__device__ __forceinline__ u16 f32_to_bf16(float f) {
  u32 b = __float_as_uint(f);
  b += 0x7fffu + ((b >> 16) & 1u);  // round to nearest even
  return (u16)(b >> 16);
}

// ---------------------------------------------------------------------------
// K1: ATOMIC-FREE adjacency build (two-pass radix), fused with convert_x.
// (r8, proven: fill path 56us -> ~35us combined, WRITE 48MB -> payload-only.)
//  scan1: per-block LDS histogram over coarse bins (dst>>8, 256 nodes/bin),
//         then ONE global atomicAdd per (block,bin) (~29k total).
//  scan2: re-read (L2-hot) edges, scatter (dst,src) pairs into bin regions.
// Blocks beyond nradix do the X fp32->bf16 convert.
// ---------------------------------------------------------------------------
__global__ __launch_bounds__(256) void front_kernel(
    const float* __restrict__ X, u16* __restrict__ Xb, int n8,
    const int* __restrict__ ra, const int* __restrict__ rb,
    int* __restrict__ gOff, int2* __restrict__ binned, int nedges, int nunits,
    int nbins, int nradix) {
  if ((int)blockIdx.x >= nradix) {
    // ---- convert_x path ----
    int i = ((int)blockIdx.x - nradix) * 256 + threadIdx.x;
    if (i >= n8) return;
    float4 a = ((const float4*)X)[2 * i];
    float4 b = ((const float4*)X)[2 * i + 1];
    int4 o;
    o.x = (int)((u32)f32_to_bf16(a.x) | ((u32)f32_to_bf16(a.y) << 16));
    o.y = (int)((u32)f32_to_bf16(a.z) | ((u32)f32_to_bf16(a.w) << 16));
    o.z = (int)((u32)f32_to_bf16(b.x) | ((u32)f32_to_bf16(b.y) << 16));
    o.w = (int)((u32)f32_to_bf16(b.z) | ((u32)f32_to_bf16(b.w) << 16));
    ((int4*)Xb)[i] = o;
    return;
  }
  // ---- radix scatter path ----
  __shared__ int lh[512];  // bin histogram, then running slot position
  const int tid = threadIdx.x;
  for (int b = tid; b < nbins; b += 256) lh[b] = 0;
  __syncthreads();
  const int u0 = (int)blockIdx.x * RADIX_UNITS;

  // scan 1: count entries per bin
  for (int k = 0; k < RADIX_UNITS / 256; ++k) {
    int u = u0 + k * 256 + tid;
    if (u < nunits) {
      long long apk = ((const long long*)ra)[u];
      long long bpk = ((const long long*)rb)[u];
      int a0 = (int)apk, a1 = (int)(apk >> 32);
      int b0 = (int)bpk, b1 = (int)(bpk >> 32);
      bool has1 = (2 * u + 1) < nedges;
      atomicAdd(&lh[a0 >> 8], 1);
      atomicAdd(&lh[b0 >> 8], 1);
      if (has1) {
        atomicAdd(&lh[a1 >> 8], 1);
        atomicAdd(&lh[b1 >> 8], 1);
      }
    }
  }
  __syncthreads();
  // reserve contiguous space per bin (one device atomic per block,bin)
  for (int b = tid; b < nbins; b += 256) {
    int c = lh[b];
    lh[b] = (c > 0) ? atomicAdd(&gOff[b], c) : 0;
  }
  __syncthreads();
  // scan 2: place (dst,src) pairs at block-contiguous slots
  for (int k = 0; k < RADIX_UNITS / 256; ++k) {
    int u = u0 + k * 256 + tid;
    if (u < nunits) {
      long long apk = ((const long long*)ra)[u];
      long long bpk = ((const long long*)rb)[u];
      int a0 = (int)apk, a1 = (int)(apk >> 32);
      int b0 = (int)bpk, b1 = (int)(bpk >> 32);
      bool has1 = (2 * u + 1) < nedges;
      int d[4], s[4];
      d[0] = a0; s[0] = b0;
      d[1] = b0; s[1] = a0;
      d[2] = has1 ? a1 : -1; s[2] = b1;
      d[3] = has1 ? b1 : -1; s[3] = a1;
#pragma unroll
      for (int i = 0; i < 4; ++i) {
        if (d[i] >= 0) {
          int b = d[i] >> 8;
          int slot = atomicAdd(&lh[b], 1);
          if (slot < BCAP) binned[(size_t)b * BCAP + slot] = make_int2(d[i], s[i]);
        }
      }
    }
  }
}

// ---------------------------------------------------------------------------
// K1b: per-bin adjacency build. One block per 256-node bin: stream the bin's
// pairs (coalesced), slot via LDS atomics, plain stores into the bin's
// contiguous 64KB adj region (L2-resident, one writeback). Writes cnt for
// every node (memset-free).
// ---------------------------------------------------------------------------
__global__ __launch_bounds__(256) void bin_build_kernel(
    const int2* __restrict__ binned, const int* __restrict__ gOff,
    int* __restrict__ cnt, int* __restrict__ adj, int nnodes) {
  __shared__ int lc[256];
  const int bin = blockIdx.x;
  lc[threadIdx.x] = 0;
  __syncthreads();
  int count = gOff[bin];
  if (count > BCAP) count = BCAP;
  const int2* src = binned + (size_t)bin * BCAP;
  for (int i = threadIdx.x; i < count; i += 256) {
    int2 e = src[i];
    int p = atomicAdd(&lc[e.x & 255], 1);
    if (p < CAP) adj[(size_t)e.x * CAP + p] = e.y;
  }
  __syncthreads();
  int node = bin * 256 + threadIdx.x;
  if (node < nnodes) cnt[node] = lc[threadIdx.x];
}

// ---------------------------------------------------------------------------
// K2 round-9: gather-aggregate, QUARTER-WAVE deep-pipelined version.
// r4 evidence: 47.5us, FETCH 147MB (3.1 TB/s of L2-miss traffic), VALUBusy
// 37%, occupancy 68% -- both pipes mid-range + random 256B granules only
// 8-deep = latency-bound, not BW-bound. Fix: 16 lanes x uint4 per node
// (1 load per 16B instead of per 8B) and a 16-deep neighbor batch
// (256B/lane in flight, 4x r4). Index reads drop to 64B/node for deg<=16
// (~90% of nodes at lambda~12). fp32 accumulate; result written as bf16 row
// into the node's own adj bucket (indices fully consumed before the store;
// buckets disjoint -> race-free).
// ---------------------------------------------------------------------------
__global__ void gather_agg_kernel(const u16* __restrict__ Xb,
                                  const int* __restrict__ cnt,
                                  int* __restrict__ adj, int nnodes) {
  int gid = blockIdx.x * blockDim.x + threadIdx.x;
  int wid = gid >> 6;
  int l = gid & 63;
  int q = l >> 4;    // quarter 0..3
  int ql = l & 15;   // lane within quarter
  int node = wid * 4 + q;
  if (node >= nnodes) return;
  const uint4* Xv = (const uint4*)Xb;  // row = 16 uint4 (256 B)
  const int* lst = adj + (size_t)node * CAP;
  int n = cnt[node];
  if (n > CAP) n = CAP;
  int idx0 = lst[ql];                      // positions 0..15
  int idx1 = (n > 16) ? lst[ql + 16] : 0;  // 16..31
  int idx2 = (n > 32) ? lst[ql + 32] : 0;  // 32..47 (rare)
  int idx3 = (n > 48) ? lst[ql + 48] : 0;  // 48..63 (rarer)
  uint4 ps = Xv[(size_t)node * 16 + ql];
  float acc[8];
  acc[0] = __uint_as_float(ps.x << 16);
  acc[1] = __uint_as_float(ps.x & 0xffff0000u);
  acc[2] = __uint_as_float(ps.y << 16);
  acc[3] = __uint_as_float(ps.y & 0xffff0000u);
  acc[4] = __uint_as_float(ps.z << 16);
  acc[5] = __uint_as_float(ps.z & 0xffff0000u);
  acc[6] = __uint_as_float(ps.w << 16);
  acc[7] = __uint_as_float(ps.w & 0xffff0000u);
  const int base = q << 4;
  for (int k = 0; k < n; k += 16) {
    uint4 pv[16];
#pragma unroll
    for (int t = 0; t < 16; ++t) {
      int pos = k + t;
      int sel = (pos < 16) ? idx0 : (pos < 32) ? idx1 : (pos < 48) ? idx2 : idx3;
      int nb = __shfl(sel, base + (pos & 15));
      pv[t] = (pos < n) ? Xv[(size_t)nb * 16 + ql] : make_uint4(0u, 0u, 0u, 0u);
    }
#pragma unroll
    for (int t = 0; t < 16; ++t) {
      acc[0] += __uint_as_float(pv[t].x << 16);
      acc[1] += __uint_as_float(pv[t].x & 0xffff0000u);
      acc[2] += __uint_as_float(pv[t].y << 16);
      acc[3] += __uint_as_float(pv[t].y & 0xffff0000u);
      acc[4] += __uint_as_float(pv[t].z << 16);
      acc[5] += __uint_as_float(pv[t].z & 0xffff0000u);
      acc[6] += __uint_as_float(pv[t].w << 16);
      acc[7] += __uint_as_float(pv[t].w & 0xffff0000u);
    }
  }
  uint4 o;
  o.x = (u32)f32_to_bf16(acc[0]) | ((u32)f32_to_bf16(acc[1]) << 16);
  o.y = (u32)f32_to_bf16(acc[2]) | ((u32)f32_to_bf16(acc[3]) << 16);
  o.z = (u32)f32_to_bf16(acc[4]) | ((u32)f32_to_bf16(acc[5]) << 16);
  o.w = (u32)f32_to_bf16(acc[6]) | ((u32)f32_to_bf16(acc[7]) << 16);
  ((uint4*)adj)[(size_t)node * 16 + ql] = o;
}

// ---------------------------------------------------------------------------
// K3: transpose+convert weights fp32 -> bf16 (W^T layout [n][k]) into the
// dead `cnt` region (runs after gather).
// ---------------------------------------------------------------------------
__global__ void convert_w_kernel(const float* __restrict__ Wh,
                                 const float* __restrict__ Wo,
                                 u16* __restrict__ WhT,
                                 u16* __restrict__ WoT) {
  int idx = blockIdx.x * 256 + threadIdx.x;  // 0..32767
  const float* src = (idx < 16384) ? Wh : Wo;
  u16* dst = (idx < 16384) ? WhT : WoT;
  int i = idx & 16383;
  int k = i >> 7, n = i & 127;
  dst[n * 128 + k] = f32_to_bf16(src[k * 128 + n]);
}

// ---------------------------------------------------------------------------
// K4: fused MLP via bf16 MFMA (16x16x32) -- r0-proven version.
// ---------------------------------------------------------------------------
__global__ __launch_bounds__(256) void mlp_mfma_kernel(
    const u16* __restrict__ Xagg,  // [nnodes][128] bf16 (lives in adj region)
    const u16* __restrict__ WhT,   // [128][128] bf16, [n][k]
    const u16* __restrict__ WoT,   // [128][128] bf16, [n][k]
    const float* __restrict__ bh,
    const float* __restrict__ bo,
    float* __restrict__ out, int nnodes) {
  __shared__ u16 smem[2 * 128 * 128];  // 64 KB
  u16* sA = smem;
  u16* sW = smem + 16384;

  const int tid = threadIdx.x;
  const int w = tid >> 6;
  const int l = tid & 63;
  const int l15 = l & 15;
  const int l4 = l >> 4;  // quad 0..3
  const int r0 = blockIdx.x * 128;

  // ---- stage sA (Xagg tile) and sW (Wh^T), swizzled 16B units ----
#pragma unroll
  for (int t = 0; t < 8; ++t) {
    int id = tid + t * 256;  // 0..2047 : 128 rows x 16 units
    int r = id >> 4, u = id & 15;
    int gr = r0 + r;
    if (gr >= nnodes) gr = nnodes - 1;
    *(int4*)&sA[r * 128 + ((u ^ (r & 15)) * 8)] =
        *(const int4*)&Xagg[(size_t)gr * 128 + u * 8];
    *(int4*)&sW[r * 128 + ((u ^ (r & 15)) * 8)] =
        *(const int4*)&WhT[r * 128 + u * 8];
  }

  float bhv[8], bov[8];
#pragma unroll
  for (int j = 0; j < 8; ++j) {
    bhv[j] = bh[j * 16 + l15];
    bov[j] = bo[j * 16 + l15];
  }
  __syncthreads();

  const int m0 = w * 32 + l15;       // A row, m-tile 0
  const int m1 = w * 32 + 16 + l15;  // A row, m-tile 1

  f32x4 acc[2][8];
#pragma unroll
  for (int i = 0; i < 2; ++i)
#pragma unroll
    for (int j = 0; j < 8; ++j) acc[i][j] = (f32x4){0.f, 0.f, 0.f, 0.f};

  // ---- GEMM1: hidden = Xagg @ Wh ----
#pragma unroll
  for (int c = 0; c < 4; ++c) {  // K chunks of 32
    int pu = ((c * 4 + l4) ^ l15) * 8;
    bf16x8 a0 = *(bf16x8*)&sA[m0 * 128 + pu];
    bf16x8 a1 = *(bf16x8*)&sA[m1 * 128 + pu];
#pragma unroll
    for (int j = 0; j < 8; ++j) {
      bf16x8 bfr = *(bf16x8*)&sW[(j * 16 + l15) * 128 + pu];
      acc[0][j] = __builtin_amdgcn_mfma_f32_16x16x32_bf16(a0, bfr, acc[0][j], 0, 0, 0);
      acc[1][j] = __builtin_amdgcn_mfma_f32_16x16x32_bf16(a1, bfr, acc[1][j], 0, 0, 0);
    }
  }

  __syncthreads();  // all waves done reading sW (GEMM1)

  // ---- restage sW with Wo^T ----
#pragma unroll
  for (int t = 0; t < 8; ++t) {
    int id = tid + t * 256;
    int r = id >> 4, u = id & 15;
    *(int4*)&sW[r * 128 + ((u ^ (r & 15)) * 8)] =
        *(const int4*)&WoT[r * 128 + u * 8];
  }

  // ---- bias + relu + bf16, write hidden into sA (own rows only) ----
#pragma unroll
  for (int i = 0; i < 2; ++i)
#pragma unroll
    for (int j = 0; j < 8; ++j)
#pragma unroll
      for (int r = 0; r < 4; ++r) {
        int m = w * 32 + i * 16 + l4 * 4 + r;
        float v = fmaxf(acc[i][j][r] + bhv[j], 0.f);
        int k = j * 16 + l15;
        sA[m * 128 + (((k >> 3) ^ (m & 15)) * 8) + (k & 7)] = f32_to_bf16(v);
      }
  __syncthreads();

  // ---- GEMM2: out = hidden @ Wo (reuse acc) ----
#pragma unroll
  for (int i = 0; i < 2; ++i)
#pragma unroll
    for (int j = 0; j < 8; ++j) acc[i][j] = (f32x4){0.f, 0.f, 0.f, 0.f};

#pragma unroll
  for (int c = 0; c < 4; ++c) {
    int pu = ((c * 4 + l4) ^ l15) * 8;
    bf16x8 a0 = *(bf16x8*)&sA[m0 * 128 + pu];
    bf16x8 a1 = *(bf16x8*)&sA[m1 * 128 + pu];
#pragma unroll
    for (int j = 0; j < 8; ++j) {
      bf16x8 bfr = *(bf16x8*)&sW[(j * 16 + l15) * 128 + pu];
      acc[0][j] = __builtin_amdgcn_mfma_f32_16x16x32_bf16(a0, bfr, acc[0][j], 0, 0, 0);
      acc[1][j] = __builtin_amdgcn_mfma_f32_16x16x32_bf16(a1, bfr, acc[1][j], 0, 0, 0);
    }
  }

  __syncthreads();  // everyone done with sA/sW -> reuse as fp32 out stage

  // ---- epilogue: + bo, stage in LDS, coalesced dwordx4 stores ----
  float* sOut = (float*)smem;  // 128 x 128 fp32 = 64 KB
#pragma unroll
  for (int i = 0; i < 2; ++i)
#pragma unroll
    for (int j = 0; j < 8; ++j)
#pragma unroll
      for (int r = 0; r < 4; ++r) {
        int m = w * 32 + i * 16 + l4 * 4 + r;
        sOut[m * 128 + j * 16 + l15] = acc[i][j][r] + bov[j];
      }
  __syncthreads();
#pragma unroll
  for (int t = 0; t < 16; ++t) {
    int id = tid + t * 256;  // 0..4095 float4 units
    int r = id >> 5, u4 = id & 31;
    int gr = r0 + r;
    if (gr < nnodes)
      ((float4*)out)[(size_t)gr * 32 + u4] = ((const float4*)sOut)[id];
  }
}

// ---------------------------------------------------------------------------
extern "C" void kernel_launch(void* const* d_in, const int* in_sizes, int n_in,
                              void* d_out, int out_size, void* d_ws,
                              size_t ws_size, hipStream_t stream) {
  const float* X = (const float*)d_in[0];
  const int* ra = (const int*)d_in[1];
  const int* rb = (const int*)d_in[2];
  const float* Wh = (const float*)d_in[3];
  const float* bh = (const float*)d_in[4];
  const float* Wo = (const float*)d_in[5];
  const float* bo = (const float*)d_in[6];
  float* out = (float*)d_out;

  int nnodes = in_sizes[0] / 128;
  int nedges = in_sizes[1];
  int nunits = (nedges + 1) / 2;         // int2 edge units
  int nbins = (nnodes + 255) >> 8;       // 256-node coarse bins
  int nradix = (nunits + RADIX_UNITS - 1) / RADIX_UNITS;

  // ws layout (proven 26.0 MB): [cnt: nnodes ints | adj: nnodes*CAP ints].
  // After gather: adj holds Xagg bf16 rows; cnt dead -> WhT/WoT overlay.
  int* cnt = (int*)d_ws;
  int* adj = cnt + nnodes;
  u16* WhT = (u16*)d_ws;
  u16* WoT = WhT + 16384;
  // d_out transient layout: [Xb: nnodes*256B | binned: nbins*BCAP*8B | gOff]
  // (binned/gOff dead before mlp writes out; Xb consumed by gather).
  u16* Xb = (u16*)d_out;
  int2* binned = (int2*)((char*)d_out + (size_t)nnodes * 256);
  int* gOff = (int*)((char*)binned + (size_t)nbins * BCAP * sizeof(int2));

  int n8 = nnodes * 16;  // 128 feats / 8 per thread
  int nconv = (n8 + 255) / 256;
  hipMemsetAsync(gOff, 0, (size_t)nbins * 4, stream);
  front_kernel<<<nradix + nconv, 256, 0, stream>>>(
      X, Xb, n8, ra, rb, gOff, binned, nedges, nunits, nbins, nradix);
  bin_build_kernel<<<nbins, 256, 0, stream>>>(binned, gOff, cnt, adj, nnodes);
  int nwaves4 = (nnodes + 3) / 4;  // 4 nodes per wave
  gather_agg_kernel<<<(nwaves4 * 64 + 255) / 256, 256, 0, stream>>>(
      Xb, cnt, adj, nnodes);
  convert_w_kernel<<<128, 256, 0, stream>>>(Wh, Wo, WhT, WoT);
  mlp_mfma_kernel<<<(nnodes + 127) / 128, 256, 0, stream>>>(
      (const u16*)adj, WhT, WoT, bh, bo, out, nnodes);
}